// Round 1
// baseline (1405.045 us; speedup 1.0000x reference)
//
#include <hip/hip_runtime.h>

#define N_NODES 50000
#define N_EDGES 800000
#define IN_DIM  768
#define HID_DIM 512
#define OUT_DIM 256

// ---------------------------------------------------------------------------
// Degree count: deg[d] += 1 for every edge destination (self-loop added later
// as the +1 inside rsqrt).
// ---------------------------------------------------------------------------
__global__ void count_deg_kernel(const int* __restrict__ dst, int* __restrict__ deg,
                                 int n_edges) {
    int e = blockIdx.x * blockDim.x + threadIdx.x;
    if (e < n_edges) atomicAdd(&deg[dst[e]], 1);
}

// ---------------------------------------------------------------------------
// Single-block exclusive scan over deg -> CSR offsets (+ cursor copy) and
// dinv[i] = rsqrt(deg[i] + 1).  50000 elements, 1024 threads, ~49 chunks.
// ---------------------------------------------------------------------------
__global__ void scan_kernel(const int* __restrict__ deg, int* __restrict__ offsets,
                            int* __restrict__ cursor, float* __restrict__ dinv, int n) {
    __shared__ int smem[1024];
    __shared__ int carry_s;
    int tid = threadIdx.x;
    if (tid == 0) carry_s = 0;
    __syncthreads();
    for (int base = 0; base < n; base += 1024) {
        int i = base + tid;
        int v = (i < n) ? deg[i] : 0;
        smem[tid] = v;
        __syncthreads();
        for (int off = 1; off < 1024; off <<= 1) {
            int t = (tid >= off) ? smem[tid - off] : 0;
            __syncthreads();
            smem[tid] += t;
            __syncthreads();
        }
        int excl  = smem[tid] - v;
        int total = smem[1023];
        int o = carry_s + excl;         // read carry before it is updated
        if (i < n) {
            offsets[i] = o;
            cursor[i]  = o;
            dinv[i]    = rsqrtf((float)(v + 1));
        }
        __syncthreads();
        if (tid == 0) carry_s += total;
        __syncthreads();
    }
    if (tid == 0) offsets[n] = carry_s;
}

// ---------------------------------------------------------------------------
// CSR fill: csr_src[cursor[dst]++] = src
// ---------------------------------------------------------------------------
__global__ void fill_csr_kernel(const int* __restrict__ src, const int* __restrict__ dst,
                                int* __restrict__ cursor, int* __restrict__ csr_src,
                                int n_edges) {
    int e = blockIdx.x * blockDim.x + threadIdx.x;
    if (e < n_edges) {
        int p = atomicAdd(&cursor[dst[e]], 1);
        csr_src[p] = src[e];
    }
}

// ---------------------------------------------------------------------------
// fp32 SIMT GEMM, C[r][c] = (sum_k A[r][k]B[k][c]) * dinv[r]
// 64x64 tile, BK=16, 256 threads, 4x4 micro-tile per thread, float4 LDS IO.
// K must be a multiple of 16; N a multiple of 64; M guarded.
// ---------------------------------------------------------------------------
#define BM 64
#define BN 64
#define BK 16
#define LDA (BM + 4)
#define LDB (BN + 4)

__global__ __launch_bounds__(256)
void gemm_scaled_kernel(const float* __restrict__ A, const float* __restrict__ B,
                        const float* __restrict__ dinv, float* __restrict__ C,
                        int M, int N, int K) {
    __shared__ float As[BK][LDA];   // transposed: As[k][m]
    __shared__ float Bs[BK][LDB];   // Bs[k][n]

    int tid = threadIdx.x;
    int rowBase = blockIdx.y * BM;
    int colBase = blockIdx.x * BN;
    int tx = tid & 15;              // 0..15  -> 4 cols each
    int ty = tid >> 4;              // 0..15  -> 4 rows each

    float acc[4][4] = {};

    for (int k0 = 0; k0 < K; k0 += BK) {
        // A tile: 64 rows x 16 k, one float4 (along K) per thread
        {
            int ar = tid >> 2;            // 0..63
            int ac = (tid & 3) * 4;       // 0,4,8,12
            int gr = rowBase + ar;
            float4 v = make_float4(0.f, 0.f, 0.f, 0.f);
            if (gr < M)
                v = *reinterpret_cast<const float4*>(A + (size_t)gr * K + k0 + ac);
            As[ac + 0][ar] = v.x;
            As[ac + 1][ar] = v.y;
            As[ac + 2][ar] = v.z;
            As[ac + 3][ar] = v.w;
        }
        // B tile: 16 k x 64 cols, one float4 (along N) per thread
        {
            int br = tid >> 4;            // 0..15
            int bc = (tid & 15) * 4;      // 0..60
            float4 v = *reinterpret_cast<const float4*>(B + (size_t)(k0 + br) * N + colBase + bc);
            *reinterpret_cast<float4*>(&Bs[br][bc]) = v;
        }
        __syncthreads();

#pragma unroll
        for (int kk = 0; kk < BK; kk++) {
            float4 av = *reinterpret_cast<const float4*>(&As[kk][ty * 4]);
            float4 bv = *reinterpret_cast<const float4*>(&Bs[kk][tx * 4]);
            float a[4] = {av.x, av.y, av.z, av.w};
            float b[4] = {bv.x, bv.y, bv.z, bv.w};
#pragma unroll
            for (int i = 0; i < 4; i++)
#pragma unroll
                for (int j = 0; j < 4; j++)
                    acc[i][j] += a[i] * b[j];
        }
        __syncthreads();
    }

#pragma unroll
    for (int i = 0; i < 4; i++) {
        int r = rowBase + ty * 4 + i;
        if (r >= M) continue;
        float dv = dinv[r];
        float4 o = make_float4(acc[i][0] * dv, acc[i][1] * dv,
                               acc[i][2] * dv, acc[i][3] * dv);
        *reinterpret_cast<float4*>(C + (size_t)r * N + colBase + tx * 4) = o;
    }
}

// ---------------------------------------------------------------------------
// Row-parallel aggregation: one block per node, blockDim = F/4.
// out[node] = act( (hs[node] + sum_{s in N(node)} hs[s]) * dinv[node] + bias )
// ---------------------------------------------------------------------------
template <int F, bool RELU>
__global__ void aggregate_kernel(const float* __restrict__ hs, const int* __restrict__ offsets,
                                 const int* __restrict__ csr_src, const float* __restrict__ dinv,
                                 const float* __restrict__ bias, float* __restrict__ out) {
    int node = blockIdx.x;
    int c = threadIdx.x * 4;

    float4 acc = *reinterpret_cast<const float4*>(hs + (size_t)node * F + c);  // self-loop
    int beg = offsets[node], end = offsets[node + 1];
    for (int i = beg; i < end; i++) {
        int s = csr_src[i];
        float4 v = *reinterpret_cast<const float4*>(hs + (size_t)s * F + c);
        acc.x += v.x; acc.y += v.y; acc.z += v.z; acc.w += v.w;
    }
    float dv = dinv[node];
    float4 b = *reinterpret_cast<const float4*>(bias + c);
    float4 o = make_float4(acc.x * dv + b.x, acc.y * dv + b.y,
                           acc.z * dv + b.z, acc.w * dv + b.w);
    if (RELU) {
        o.x = fmaxf(o.x, 0.f); o.y = fmaxf(o.y, 0.f);
        o.z = fmaxf(o.z, 0.f); o.w = fmaxf(o.w, 0.f);
    }
    *reinterpret_cast<float4*>(out + (size_t)node * F + c) = o;
}

// ---------------------------------------------------------------------------
extern "C" void kernel_launch(void* const* d_in, const int* in_sizes, int n_in,
                              void* d_out, int out_size, void* d_ws, size_t ws_size,
                              hipStream_t stream) {
    const float* x    = (const float*)d_in[0];
    const int*   edge = (const int*)d_in[1];
    const float* W1   = (const float*)d_in[2];
    const float* b1   = (const float*)d_in[3];
    const float* W2   = (const float*)d_in[4];
    const float* b2   = (const float*)d_in[5];
    float* out = (float*)d_out;

    const int* src = edge;            // edge_index[0][:]
    const int* dst = edge + N_EDGES;  // edge_index[1][:]

    // workspace carve-up (256B aligned)
    char*  ws  = (char*)d_ws;
    size_t off = 0;
    auto alloc = [&](size_t bytes) -> void* {
        void* p = ws + off;
        off += (bytes + 255) & ~(size_t)255;
        return p;
    };
    int*   deg     = (int*)alloc((size_t)N_NODES * 4);
    float* dinv    = (float*)alloc((size_t)N_NODES * 4);
    int*   offsets = (int*)alloc((size_t)(N_NODES + 1) * 4);
    int*   cursor  = (int*)alloc((size_t)N_NODES * 4);
    int*   csr_src = (int*)alloc((size_t)N_EDGES * 4);
    float* hs1     = (float*)alloc((size_t)N_NODES * HID_DIM * 4);
    float* y1      = (float*)alloc((size_t)N_NODES * HID_DIM * 4);
    float* hs2     = hs1;  // hs1 dead after aggregate1; reuse for layer-2 pre-agg

    // ---- graph prep (shared by both layers) ----
    hipMemsetAsync(deg, 0, (size_t)N_NODES * 4, stream);
    count_deg_kernel<<<(N_EDGES + 255) / 256, 256, 0, stream>>>(dst, deg, N_EDGES);
    scan_kernel<<<1, 1024, 0, stream>>>(deg, offsets, cursor, dinv, N_NODES);
    fill_csr_kernel<<<(N_EDGES + 255) / 256, 256, 0, stream>>>(src, dst, cursor, csr_src, N_EDGES);

    // ---- layer 1 ----
    dim3 g1(HID_DIM / BN, (N_NODES + BM - 1) / BM);
    gemm_scaled_kernel<<<g1, 256, 0, stream>>>(x, W1, dinv, hs1, N_NODES, HID_DIM, IN_DIM);
    aggregate_kernel<HID_DIM, true><<<N_NODES, HID_DIM / 4, 0, stream>>>(
        hs1, offsets, csr_src, dinv, b1, y1);

    // ---- layer 2 ----
    dim3 g2(OUT_DIM / BN, (N_NODES + BM - 1) / BM);
    gemm_scaled_kernel<<<g2, 256, 0, stream>>>(y1, W2, dinv, hs2, N_NODES, OUT_DIM, HID_DIM);
    aggregate_kernel<OUT_DIM, false><<<N_NODES, OUT_DIM / 4, 0, stream>>>(
        hs2, offsets, csr_src, dinv, b2, out);
}

// Round 2
// 1041.927 us; speedup vs baseline: 1.3485x; 1.3485x over previous
//
#include <hip/hip_runtime.h>

#define N_NODES 50000
#define N_EDGES 800000
#define IN_DIM  768
#define HID_DIM 512
#define OUT_DIM 256
#define M_PAD   50048   // 391 * 128

typedef __attribute__((ext_vector_type(8))) short shortx8;   // 8 bf16 = 4 VGPRs
typedef __attribute__((ext_vector_type(4))) float floatx4;   // MFMA C/D

#define AS1 __attribute__((address_space(1)))
#define AS3 __attribute__((address_space(3)))

__device__ __forceinline__ unsigned short f2bf_rne(float f) {
    unsigned int u = __float_as_uint(f);
    unsigned int r = u + 0x7FFFu + ((u >> 16) & 1u);
    return (unsigned short)(r >> 16);
}
__device__ __forceinline__ float bf2f(unsigned short h) {
    return __uint_as_float(((unsigned int)h) << 16);
}

// ---------------------------------------------------------------------------
// Graph prep
// ---------------------------------------------------------------------------
__global__ void count_deg_kernel(const int* __restrict__ dst, int* __restrict__ deg,
                                 int n_edges) {
    int e = blockIdx.x * blockDim.x + threadIdx.x;
    if (e < n_edges) atomicAdd(&deg[dst[e]], 1);
}

__global__ void scan_kernel(const int* __restrict__ deg, int* __restrict__ offsets,
                            int* __restrict__ cursor, float* __restrict__ dinv, int n) {
    __shared__ int smem[1024];
    __shared__ int carry_s;
    int tid = threadIdx.x;
    if (tid == 0) carry_s = 0;
    __syncthreads();
    for (int base = 0; base < n; base += 1024) {
        int i = base + tid;
        int v = (i < n) ? deg[i] : 0;
        smem[tid] = v;
        __syncthreads();
        for (int off = 1; off < 1024; off <<= 1) {
            int t = (tid >= off) ? smem[tid - off] : 0;
            __syncthreads();
            smem[tid] += t;
            __syncthreads();
        }
        int excl  = smem[tid] - v;
        int total = smem[1023];
        int o = carry_s + excl;
        if (i < n) {
            offsets[i] = o;
            cursor[i]  = o;
            dinv[i]    = rsqrtf((float)(v + 1));
        }
        __syncthreads();
        if (tid == 0) carry_s += total;
        __syncthreads();
    }
    if (tid == 0) offsets[n] = carry_s;
}

__global__ void fill_csr_kernel(const int* __restrict__ src, const int* __restrict__ dst,
                                int* __restrict__ cursor, int* __restrict__ csr_src,
                                int n_edges) {
    int e = blockIdx.x * blockDim.x + threadIdx.x;
    if (e < n_edges) {
        int p = atomicAdd(&cursor[dst[e]], 1);
        csr_src[p] = src[e];
    }
}

// ---------------------------------------------------------------------------
// fp32 -> bf16 hi/lo split (flat copy; row layout identical, padding untouched)
// ---------------------------------------------------------------------------
__global__ void convert_split_kernel(const float* __restrict__ x,
                                     unsigned short* __restrict__ xhi,
                                     unsigned short* __restrict__ xlo,
                                     long long n4) {
    long long i = (long long)blockIdx.x * blockDim.x + threadIdx.x;
    if (i >= n4) return;
    float4 v = *reinterpret_cast<const float4*>(x + i * 4);
    ushort4 h, l;
    h.x = f2bf_rne(v.x); l.x = f2bf_rne(v.x - bf2f(h.x));
    h.y = f2bf_rne(v.y); l.y = f2bf_rne(v.y - bf2f(h.y));
    h.z = f2bf_rne(v.z); l.z = f2bf_rne(v.z - bf2f(h.z));
    h.w = f2bf_rne(v.w); l.w = f2bf_rne(v.w - bf2f(h.w));
    *reinterpret_cast<ushort4*>(xhi + i * 4) = h;
    *reinterpret_cast<ushort4*>(xlo + i * 4) = l;
}

// ---------------------------------------------------------------------------
// W [K][N] fp32 -> Wt [N][K] bf16 hi/lo  (32x32 LDS tile transpose)
// ---------------------------------------------------------------------------
__global__ void transpose_split_kernel(const float* __restrict__ W,
                                       unsigned short* __restrict__ Whi,
                                       unsigned short* __restrict__ Wlo,
                                       int K, int N) {
    __shared__ float tile[32][33];
    int n0 = blockIdx.x * 32, k0 = blockIdx.y * 32;
    int tx = threadIdx.x, ty = threadIdx.y;
    tile[ty][tx] = W[(size_t)(k0 + ty) * N + n0 + tx];
    __syncthreads();
    float v = tile[tx][ty];                      // = W[k0+tx][n0+ty]
    unsigned short h = f2bf_rne(v);
    size_t o = (size_t)(n0 + ty) * K + k0 + tx;  // coalesced in tx
    Whi[o] = h;
    Wlo[o] = f2bf_rne(v - bf2f(h));
}

// ---------------------------------------------------------------------------
// bf16x3 split MFMA GEMM:  C[r][c] = (sum_k A[r][k]*B[c][k]) * dinv[r]
//   A (hi/lo): [M_pad][K] bf16 row-major, M_pad multiple of 128
//   B (hi/lo): [N][K]     bf16 row-major (pre-transposed weight)
// 128x128 block tile, BK=32, 256 threads = 4 waves (2x2), 64x64 per wave,
// 4x4 subtiles of v_mfma_f32_16x16x32_bf16, 3 MFMA per subtile (hh, hl, lh).
// Staging via global_load_lds width=16 (wave-uniform base + lane*16).
// ---------------------------------------------------------------------------
#define GBK 32

__global__ __launch_bounds__(256)
void gemm_bf16x3_kernel(const unsigned short* __restrict__ Ahi,
                        const unsigned short* __restrict__ Alo,
                        const unsigned short* __restrict__ Bhi,
                        const unsigned short* __restrict__ Blo,
                        const float* __restrict__ dinv, float* __restrict__ C,
                        int M, int N, int K) {
    __shared__ __align__(16) unsigned short As[2][128][GBK];  // [hi/lo][m][k]
    __shared__ __align__(16) unsigned short Bs[2][128][GBK];  // [hi/lo][n][k]

    const int tid  = threadIdx.x;
    const int lane = tid & 63;
    const int wave = tid >> 6;            // 0..3
    const int rowBase = blockIdx.y * 128;
    const int colBase = blockIdx.x * 128;

    // this wave's staging target: 0->As.hi 1->As.lo 2->Bs.hi 3->Bs.lo
    const unsigned short* gsrc =
        (wave == 0) ? Ahi : (wave == 1) ? Alo : (wave == 2) ? Bhi : Blo;
    unsigned short* lbase =
        (wave == 0) ? &As[0][0][0] : (wave == 1) ? &As[1][0][0]
      : (wave == 2) ? &Bs[0][0][0] : &Bs[1][0][0];
    const int rbase = (wave < 2) ? rowBase : colBase;
    const size_t laneRowOff = (size_t)(rbase + (lane >> 2)) * K + (lane & 3) * 8;

    const int m0 = (wave & 1) * 64;
    const int n0 = (wave >> 1) * 64;
    const int r16 = lane & 15;
    const int kq  = (lane >> 4) * 8;      // k-offset of this lane's 8 elements

    floatx4 acc[4][4] = {};

    for (int k0 = 0; k0 < K; k0 += GBK) {
        // ---- stage: 8 x 1KB wave-loads, 16 rows each ----
#pragma unroll
        for (int j = 0; j < 8; j++) {
            const unsigned short* g = gsrc + laneRowOff + (size_t)(j * 16) * K + k0;
            __builtin_amdgcn_global_load_lds((const AS1 void*)g,
                                             (AS3 void*)(lbase + j * 16 * GBK),
                                             16, 0, 0);
        }
        __syncthreads();

        // ---- fragments ----
        shortx8 ah[4], al[4], bh[4], bl[4];
#pragma unroll
        for (int i = 0; i < 4; i++) {
            ah[i] = *reinterpret_cast<const shortx8*>(&As[0][m0 + i * 16 + r16][kq]);
            al[i] = *reinterpret_cast<const shortx8*>(&As[1][m0 + i * 16 + r16][kq]);
            bh[i] = *reinterpret_cast<const shortx8*>(&Bs[0][n0 + i * 16 + r16][kq]);
            bl[i] = *reinterpret_cast<const shortx8*>(&Bs[1][n0 + i * 16 + r16][kq]);
        }
#pragma unroll
        for (int i = 0; i < 4; i++)
#pragma unroll
            for (int j = 0; j < 4; j++) {
                acc[i][j] = __builtin_amdgcn_mfma_f32_16x16x32_bf16(ah[i], bh[j], acc[i][j], 0, 0, 0);
                acc[i][j] = __builtin_amdgcn_mfma_f32_16x16x32_bf16(ah[i], bl[j], acc[i][j], 0, 0, 0);
                acc[i][j] = __builtin_amdgcn_mfma_f32_16x16x32_bf16(al[i], bh[j], acc[i][j], 0, 0, 0);
            }
        __syncthreads();
    }

    // ---- epilogue: C[row][col] = acc * dinv[row] ----
    // D layout (verified m89/m91): col = lane&15, row = (lane>>4)*4 + reg
#pragma unroll
    for (int i = 0; i < 4; i++) {
        int rsub = rowBase + m0 + i * 16 + (lane >> 4) * 4;
#pragma unroll
        for (int j = 0; j < 4; j++) {
            int col = colBase + n0 + j * 16 + r16;
#pragma unroll
            for (int r = 0; r < 4; r++) {
                int row = rsub + r;
                if (row < M) C[(size_t)row * N + col] = acc[i][j][r] * dinv[row];
            }
        }
    }
}

// ---------------------------------------------------------------------------
// Aggregation, layer 1: out = relu((hs[self] + sum hs[nbr]) * dinv + b),
// written as bf16 hi/lo split (feeds gemm2).
// ---------------------------------------------------------------------------
__global__ void aggregate1_kernel(const float* __restrict__ hs, const int* __restrict__ offsets,
                                  const int* __restrict__ csr_src, const float* __restrict__ dinv,
                                  const float* __restrict__ bias,
                                  unsigned short* __restrict__ yhi,
                                  unsigned short* __restrict__ ylo) {
    const int F = HID_DIM;
    int node = blockIdx.x;
    int c = threadIdx.x * 4;

    float4 acc = *reinterpret_cast<const float4*>(hs + (size_t)node * F + c);
    int beg = offsets[node], end = offsets[node + 1];
    for (int i = beg; i < end; i++) {
        int s = csr_src[i];
        float4 v = *reinterpret_cast<const float4*>(hs + (size_t)s * F + c);
        acc.x += v.x; acc.y += v.y; acc.z += v.z; acc.w += v.w;
    }
    float dv = dinv[node];
    float4 b = *reinterpret_cast<const float4*>(bias + c);
    float4 o = make_float4(fmaxf(acc.x * dv + b.x, 0.f), fmaxf(acc.y * dv + b.y, 0.f),
                           fmaxf(acc.z * dv + b.z, 0.f), fmaxf(acc.w * dv + b.w, 0.f));
    ushort4 h, l;
    h.x = f2bf_rne(o.x); l.x = f2bf_rne(o.x - bf2f(h.x));
    h.y = f2bf_rne(o.y); l.y = f2bf_rne(o.y - bf2f(h.y));
    h.z = f2bf_rne(o.z); l.z = f2bf_rne(o.z - bf2f(h.z));
    h.w = f2bf_rne(o.w); l.w = f2bf_rne(o.w - bf2f(h.w));
    *reinterpret_cast<ushort4*>(yhi + (size_t)node * F + c) = h;
    *reinterpret_cast<ushort4*>(ylo + (size_t)node * F + c) = l;
}

// ---------------------------------------------------------------------------
// Aggregation, layer 2: fp32 out, no activation.
// ---------------------------------------------------------------------------
__global__ void aggregate2_kernel(const float* __restrict__ hs, const int* __restrict__ offsets,
                                  const int* __restrict__ csr_src, const float* __restrict__ dinv,
                                  const float* __restrict__ bias, float* __restrict__ out) {
    const int F = OUT_DIM;
    int node = blockIdx.x;
    int c = threadIdx.x * 4;

    float4 acc = *reinterpret_cast<const float4*>(hs + (size_t)node * F + c);
    int beg = offsets[node], end = offsets[node + 1];
    for (int i = beg; i < end; i++) {
        int s = csr_src[i];
        float4 v = *reinterpret_cast<const float4*>(hs + (size_t)s * F + c);
        acc.x += v.x; acc.y += v.y; acc.z += v.z; acc.w += v.w;
    }
    float dv = dinv[node];
    float4 b = *reinterpret_cast<const float4*>(bias + c);
    float4 o = make_float4(acc.x * dv + b.x, acc.y * dv + b.y,
                           acc.z * dv + b.z, acc.w * dv + b.w);
    *reinterpret_cast<float4*>(out + (size_t)node * F + c) = o;
}

// ---------------------------------------------------------------------------
extern "C" void kernel_launch(void* const* d_in, const int* in_sizes, int n_in,
                              void* d_out, int out_size, void* d_ws, size_t ws_size,
                              hipStream_t stream) {
    const float* x    = (const float*)d_in[0];
    const int*   edge = (const int*)d_in[1];
    const float* W1   = (const float*)d_in[2];
    const float* b1   = (const float*)d_in[3];
    const float* W2   = (const float*)d_in[4];
    const float* b2   = (const float*)d_in[5];
    float* out = (float*)d_out;

    const int* src = edge;
    const int* dst = edge + N_EDGES;

    char*  ws  = (char*)d_ws;
    size_t off = 0;
    auto alloc = [&](size_t bytes) -> void* {
        void* p = ws + off;
        off += (bytes + 255) & ~(size_t)255;
        return p;
    };
    int*   deg     = (int*)alloc((size_t)N_NODES * 4);
    float* dinv    = (float*)alloc((size_t)N_NODES * 4);
    int*   offsets = (int*)alloc((size_t)(N_NODES + 1) * 4);
    int*   cursor  = (int*)alloc((size_t)N_NODES * 4);
    int*   csr_src = (int*)alloc((size_t)N_EDGES * 4);
    unsigned short* xhi   = (unsigned short*)alloc((size_t)M_PAD * IN_DIM * 2);
    unsigned short* xlo   = (unsigned short*)alloc((size_t)M_PAD * IN_DIM * 2);
    unsigned short* w1thi = (unsigned short*)alloc((size_t)HID_DIM * IN_DIM * 2);
    unsigned short* w1tlo = (unsigned short*)alloc((size_t)HID_DIM * IN_DIM * 2);
    unsigned short* w2thi = (unsigned short*)alloc((size_t)OUT_DIM * HID_DIM * 2);
    unsigned short* w2tlo = (unsigned short*)alloc((size_t)OUT_DIM * HID_DIM * 2);
    float* hs = (float*)alloc((size_t)N_NODES * HID_DIM * 4);  // layer1 pre-agg; reused layer2

    // y1 hi/lo alias the dead x hi/lo regions (51.2 MB each fits in 76.9 MB)
    unsigned short* y1hi = xhi;
    unsigned short* y1lo = xlo;

    // ---- graph prep ----
    hipMemsetAsync(deg, 0, (size_t)N_NODES * 4, stream);
    count_deg_kernel<<<(N_EDGES + 255) / 256, 256, 0, stream>>>(dst, deg, N_EDGES);
    scan_kernel<<<1, 1024, 0, stream>>>(deg, offsets, cursor, dinv, N_NODES);
    fill_csr_kernel<<<(N_EDGES + 255) / 256, 256, 0, stream>>>(src, dst, cursor, csr_src, N_EDGES);

    // ---- precision split ----
    long long n4x = (long long)N_NODES * IN_DIM / 4;
    convert_split_kernel<<<(int)((n4x + 255) / 256), 256, 0, stream>>>(x, xhi, xlo, n4x);
    transpose_split_kernel<<<dim3(HID_DIM / 32, IN_DIM / 32), dim3(32, 32), 0, stream>>>(
        W1, w1thi, w1tlo, IN_DIM, HID_DIM);
    transpose_split_kernel<<<dim3(OUT_DIM / 32, HID_DIM / 32), dim3(32, 32), 0, stream>>>(
        W2, w2thi, w2tlo, HID_DIM, OUT_DIM);

    // ---- layer 1 ----
    gemm_bf16x3_kernel<<<dim3(HID_DIM / 128, M_PAD / 128), 256, 0, stream>>>(
        xhi, xlo, w1thi, w1tlo, dinv, hs, N_NODES, HID_DIM, IN_DIM);
    aggregate1_kernel<<<N_NODES, HID_DIM / 4, 0, stream>>>(
        hs, offsets, csr_src, dinv, b1, y1hi, y1lo);

    // ---- layer 2 ----
    gemm_bf16x3_kernel<<<dim3(OUT_DIM / 128, M_PAD / 128), 256, 0, stream>>>(
        y1hi, y1lo, w2thi, w2tlo, dinv, hs, N_NODES, OUT_DIM, HID_DIM);
    aggregate2_kernel<<<N_NODES, OUT_DIM / 4, 0, stream>>>(
        hs, offsets, csr_src, dinv, b2, out);
}

// Round 3
// 954.245 us; speedup vs baseline: 1.4724x; 1.0919x over previous
//
#include <hip/hip_runtime.h>

#define N_NODES 50000
#define N_EDGES 800000
#define IN_DIM  768
#define HID_DIM 512
#define OUT_DIM 256
#define M_PAD   50048   // 391 * 128

typedef __attribute__((ext_vector_type(8))) short shortx8;   // 8 bf16 = 4 VGPRs
typedef __attribute__((ext_vector_type(4))) float floatx4;   // MFMA C/D

#define AS1 __attribute__((address_space(1)))
#define AS3 __attribute__((address_space(3)))

__device__ __forceinline__ unsigned short f2bf_rne(float f) {
    unsigned int u = __float_as_uint(f);
    unsigned int r = u + 0x7FFFu + ((u >> 16) & 1u);
    return (unsigned short)(r >> 16);
}
__device__ __forceinline__ float bf2f(unsigned short h) {
    return __uint_as_float(((unsigned int)h) << 16);
}

// ---------------------------------------------------------------------------
// Graph prep
// ---------------------------------------------------------------------------
__global__ void count_deg_kernel(const int* __restrict__ dst, int* __restrict__ deg,
                                 int n_edges) {
    int e = blockIdx.x * blockDim.x + threadIdx.x;
    if (e < n_edges) atomicAdd(&deg[dst[e]], 1);
}

// ---- hierarchical exclusive scan over deg (3 small kernels) ----
#define SCAN_B 256
#define N_SCAN_BLOCKS ((N_NODES + SCAN_B - 1) / SCAN_B)   // 196

__global__ void block_sum_kernel(const int* __restrict__ deg, int* __restrict__ partials,
                                 int n) {
    __shared__ int sm[SCAN_B];
    int i = blockIdx.x * SCAN_B + threadIdx.x;
    sm[threadIdx.x] = (i < n) ? deg[i] : 0;
    __syncthreads();
    for (int off = SCAN_B / 2; off > 0; off >>= 1) {
        if (threadIdx.x < off) sm[threadIdx.x] += sm[threadIdx.x + off];
        __syncthreads();
    }
    if (threadIdx.x == 0) partials[blockIdx.x] = sm[0];
}

__global__ void scan_partials_kernel(const int* __restrict__ partials,
                                     int* __restrict__ bases, int nb) {
    __shared__ int sm[SCAN_B];
    int v = (threadIdx.x < nb) ? partials[threadIdx.x] : 0;
    sm[threadIdx.x] = v;
    __syncthreads();
    for (int off = 1; off < SCAN_B; off <<= 1) {
        int t = (threadIdx.x >= off) ? sm[threadIdx.x - off] : 0;
        __syncthreads();
        sm[threadIdx.x] += t;
        __syncthreads();
    }
    if (threadIdx.x < nb) bases[threadIdx.x] = sm[threadIdx.x] - v;   // exclusive
}

__global__ void finalize_scan_kernel(const int* __restrict__ deg, const int* __restrict__ bases,
                                     int* __restrict__ offsets, int* __restrict__ cursor,
                                     float* __restrict__ dinv, int n) {
    __shared__ int sm[SCAN_B];
    int i = blockIdx.x * SCAN_B + threadIdx.x;
    int v = (i < n) ? deg[i] : 0;
    sm[threadIdx.x] = v;
    __syncthreads();
    for (int off = 1; off < SCAN_B; off <<= 1) {
        int t = (threadIdx.x >= off) ? sm[threadIdx.x - off] : 0;
        __syncthreads();
        sm[threadIdx.x] += t;
        __syncthreads();
    }
    if (i < n) {
        int incl = bases[blockIdx.x] + sm[threadIdx.x];
        int o = incl - v;
        offsets[i] = o;
        cursor[i]  = o;
        dinv[i]    = rsqrtf((float)(v + 1));
        if (i == n - 1) offsets[n] = incl;
    }
}

__global__ void fill_csr_kernel(const int* __restrict__ src, const int* __restrict__ dst,
                                int* __restrict__ cursor, int* __restrict__ csr_src,
                                int n_edges) {
    int e = blockIdx.x * blockDim.x + threadIdx.x;
    if (e < n_edges) {
        int p = atomicAdd(&cursor[dst[e]], 1);
        csr_src[p] = src[e];
    }
}

// ---------------------------------------------------------------------------
// fp32 -> bf16 hi/lo split
// ---------------------------------------------------------------------------
__global__ void convert_split_kernel(const float* __restrict__ x,
                                     unsigned short* __restrict__ xhi,
                                     unsigned short* __restrict__ xlo,
                                     long long n4) {
    long long i = (long long)blockIdx.x * blockDim.x + threadIdx.x;
    if (i >= n4) return;
    float4 v = *reinterpret_cast<const float4*>(x + i * 4);
    ushort4 h, l;
    h.x = f2bf_rne(v.x); l.x = f2bf_rne(v.x - bf2f(h.x));
    h.y = f2bf_rne(v.y); l.y = f2bf_rne(v.y - bf2f(h.y));
    h.z = f2bf_rne(v.z); l.z = f2bf_rne(v.z - bf2f(h.z));
    h.w = f2bf_rne(v.w); l.w = f2bf_rne(v.w - bf2f(h.w));
    *reinterpret_cast<ushort4*>(xhi + i * 4) = h;
    *reinterpret_cast<ushort4*>(xlo + i * 4) = l;
}

// ---------------------------------------------------------------------------
// W [K][N] fp32 -> Wt [N][K] bf16 hi/lo
// ---------------------------------------------------------------------------
__global__ void transpose_split_kernel(const float* __restrict__ W,
                                       unsigned short* __restrict__ Whi,
                                       unsigned short* __restrict__ Wlo,
                                       int K, int N) {
    __shared__ float tile[32][33];
    int n0 = blockIdx.x * 32, k0 = blockIdx.y * 32;
    int tx = threadIdx.x, ty = threadIdx.y;
    tile[ty][tx] = W[(size_t)(k0 + ty) * N + n0 + tx];
    __syncthreads();
    float v = tile[tx][ty];
    unsigned short h = f2bf_rne(v);
    size_t o = (size_t)(n0 + ty) * K + k0 + tx;
    Whi[o] = h;
    Wlo[o] = f2bf_rne(v - bf2f(h));
}

// ---------------------------------------------------------------------------
// bf16x3 split MFMA GEMM (unchanged from round 2 — verified correct)
// ---------------------------------------------------------------------------
#define GBK 32

__global__ __launch_bounds__(256)
void gemm_bf16x3_kernel(const unsigned short* __restrict__ Ahi,
                        const unsigned short* __restrict__ Alo,
                        const unsigned short* __restrict__ Bhi,
                        const unsigned short* __restrict__ Blo,
                        const float* __restrict__ dinv, float* __restrict__ C,
                        int M, int N, int K) {
    __shared__ __align__(16) unsigned short As[2][128][GBK];
    __shared__ __align__(16) unsigned short Bs[2][128][GBK];

    const int tid  = threadIdx.x;
    const int lane = tid & 63;
    const int wave = tid >> 6;
    const int rowBase = blockIdx.y * 128;
    const int colBase = blockIdx.x * 128;

    const unsigned short* gsrc =
        (wave == 0) ? Ahi : (wave == 1) ? Alo : (wave == 2) ? Bhi : Blo;
    unsigned short* lbase =
        (wave == 0) ? &As[0][0][0] : (wave == 1) ? &As[1][0][0]
      : (wave == 2) ? &Bs[0][0][0] : &Bs[1][0][0];
    const int rbase = (wave < 2) ? rowBase : colBase;
    const size_t laneRowOff = (size_t)(rbase + (lane >> 2)) * K + (lane & 3) * 8;

    const int m0 = (wave & 1) * 64;
    const int n0 = (wave >> 1) * 64;
    const int r16 = lane & 15;
    const int kq  = (lane >> 4) * 8;

    floatx4 acc[4][4] = {};

    for (int k0 = 0; k0 < K; k0 += GBK) {
#pragma unroll
        for (int j = 0; j < 8; j++) {
            const unsigned short* g = gsrc + laneRowOff + (size_t)(j * 16) * K + k0;
            __builtin_amdgcn_global_load_lds((const AS1 void*)g,
                                             (AS3 void*)(lbase + j * 16 * GBK),
                                             16, 0, 0);
        }
        __syncthreads();

        shortx8 ah[4], al[4], bh[4], bl[4];
#pragma unroll
        for (int i = 0; i < 4; i++) {
            ah[i] = *reinterpret_cast<const shortx8*>(&As[0][m0 + i * 16 + r16][kq]);
            al[i] = *reinterpret_cast<const shortx8*>(&As[1][m0 + i * 16 + r16][kq]);
            bh[i] = *reinterpret_cast<const shortx8*>(&Bs[0][n0 + i * 16 + r16][kq]);
            bl[i] = *reinterpret_cast<const shortx8*>(&Bs[1][n0 + i * 16 + r16][kq]);
        }
#pragma unroll
        for (int i = 0; i < 4; i++)
#pragma unroll
            for (int j = 0; j < 4; j++) {
                acc[i][j] = __builtin_amdgcn_mfma_f32_16x16x32_bf16(ah[i], bh[j], acc[i][j], 0, 0, 0);
                acc[i][j] = __builtin_amdgcn_mfma_f32_16x16x32_bf16(ah[i], bl[j], acc[i][j], 0, 0, 0);
                acc[i][j] = __builtin_amdgcn_mfma_f32_16x16x32_bf16(al[i], bh[j], acc[i][j], 0, 0, 0);
            }
        __syncthreads();
    }

#pragma unroll
    for (int i = 0; i < 4; i++) {
        int rsub = rowBase + m0 + i * 16 + (lane >> 4) * 4;
#pragma unroll
        for (int j = 0; j < 4; j++) {
            int col = colBase + n0 + j * 16 + r16;
#pragma unroll
            for (int r = 0; r < 4; r++) {
                int row = rsub + r;
                if (row < M) C[(size_t)row * N + col] = acc[i][j][r] * dinv[row];
            }
        }
    }
}

// ---------------------------------------------------------------------------
// Aggregation, layer 1 (F=512, block=128): ×4-unrolled neighbor gather for MLP.
// out = relu((hs[self] + sum hs[nbr]) * dinv + b), written bf16 hi/lo.
// ---------------------------------------------------------------------------
__global__ __launch_bounds__(128)
void aggregate1_kernel(const float* __restrict__ hs, const int* __restrict__ offsets,
                       const int* __restrict__ csr_src, const float* __restrict__ dinv,
                       const float* __restrict__ bias,
                       unsigned short* __restrict__ yhi,
                       unsigned short* __restrict__ ylo) {
    const int F = HID_DIM;
    int node = blockIdx.x;
    int c = threadIdx.x * 4;
    const float* hp = hs + c;

    float4 acc = *reinterpret_cast<const float4*>(hp + (size_t)node * F);  // self-loop
    int beg = offsets[node], end = offsets[node + 1];
    int i = beg;
    for (; i + 4 <= end; i += 4) {
        int s0 = csr_src[i + 0], s1 = csr_src[i + 1];
        int s2 = csr_src[i + 2], s3 = csr_src[i + 3];
        float4 v0 = *reinterpret_cast<const float4*>(hp + (size_t)s0 * F);
        float4 v1 = *reinterpret_cast<const float4*>(hp + (size_t)s1 * F);
        float4 v2 = *reinterpret_cast<const float4*>(hp + (size_t)s2 * F);
        float4 v3 = *reinterpret_cast<const float4*>(hp + (size_t)s3 * F);
        acc.x += v0.x + v1.x + v2.x + v3.x;
        acc.y += v0.y + v1.y + v2.y + v3.y;
        acc.z += v0.z + v1.z + v2.z + v3.z;
        acc.w += v0.w + v1.w + v2.w + v3.w;
    }
    for (; i < end; i++) {
        int s = csr_src[i];
        float4 v = *reinterpret_cast<const float4*>(hp + (size_t)s * F);
        acc.x += v.x; acc.y += v.y; acc.z += v.z; acc.w += v.w;
    }
    float dv = dinv[node];
    float4 b = *reinterpret_cast<const float4*>(bias + c);
    float4 o = make_float4(fmaxf(acc.x * dv + b.x, 0.f), fmaxf(acc.y * dv + b.y, 0.f),
                           fmaxf(acc.z * dv + b.z, 0.f), fmaxf(acc.w * dv + b.w, 0.f));
    ushort4 h, l;
    h.x = f2bf_rne(o.x); l.x = f2bf_rne(o.x - bf2f(h.x));
    h.y = f2bf_rne(o.y); l.y = f2bf_rne(o.y - bf2f(h.y));
    h.z = f2bf_rne(o.z); l.z = f2bf_rne(o.z - bf2f(h.z));
    h.w = f2bf_rne(o.w); l.w = f2bf_rne(o.w - bf2f(h.w));
    *reinterpret_cast<ushort4*>(yhi + (size_t)node * F + c) = h;
    *reinterpret_cast<ushort4*>(ylo + (size_t)node * F + c) = l;
}

// ---------------------------------------------------------------------------
// Aggregation, layer 2 (F=256, block=64 = one wave): ×4-unrolled, fp32 out.
// ---------------------------------------------------------------------------
__global__ __launch_bounds__(64)
void aggregate2_kernel(const float* __restrict__ hs, const int* __restrict__ offsets,
                       const int* __restrict__ csr_src, const float* __restrict__ dinv,
                       const float* __restrict__ bias, float* __restrict__ out) {
    const int F = OUT_DIM;
    int node = blockIdx.x;
    int c = threadIdx.x * 4;
    const float* hp = hs + c;

    float4 acc = *reinterpret_cast<const float4*>(hp + (size_t)node * F);
    int beg = offsets[node], end = offsets[node + 1];
    int i = beg;
    for (; i + 4 <= end; i += 4) {
        int s0 = csr_src[i + 0], s1 = csr_src[i + 1];
        int s2 = csr_src[i + 2], s3 = csr_src[i + 3];
        float4 v0 = *reinterpret_cast<const float4*>(hp + (size_t)s0 * F);
        float4 v1 = *reinterpret_cast<const float4*>(hp + (size_t)s1 * F);
        float4 v2 = *reinterpret_cast<const float4*>(hp + (size_t)s2 * F);
        float4 v3 = *reinterpret_cast<const float4*>(hp + (size_t)s3 * F);
        acc.x += v0.x + v1.x + v2.x + v3.x;
        acc.y += v0.y + v1.y + v2.y + v3.y;
        acc.z += v0.z + v1.z + v2.z + v3.z;
        acc.w += v0.w + v1.w + v2.w + v3.w;
    }
    for (; i < end; i++) {
        int s = csr_src[i];
        float4 v = *reinterpret_cast<const float4*>(hp + (size_t)s * F);
        acc.x += v.x; acc.y += v.y; acc.z += v.z; acc.w += v.w;
    }
    float dv = dinv[node];
    float4 b = *reinterpret_cast<const float4*>(bias + c);
    float4 o = make_float4(acc.x * dv + b.x, acc.y * dv + b.y,
                           acc.z * dv + b.z, acc.w * dv + b.w);
    *reinterpret_cast<float4*>(out + (size_t)node * F + c) = o;
}

// ---------------------------------------------------------------------------
extern "C" void kernel_launch(void* const* d_in, const int* in_sizes, int n_in,
                              void* d_out, int out_size, void* d_ws, size_t ws_size,
                              hipStream_t stream) {
    const float* x    = (const float*)d_in[0];
    const int*   edge = (const int*)d_in[1];
    const float* W1   = (const float*)d_in[2];
    const float* b1   = (const float*)d_in[3];
    const float* W2   = (const float*)d_in[4];
    const float* b2   = (const float*)d_in[5];
    float* out = (float*)d_out;

    const int* src = edge;
    const int* dst = edge + N_EDGES;

    char*  ws  = (char*)d_ws;
    size_t off = 0;
    auto alloc = [&](size_t bytes) -> void* {
        void* p = ws + off;
        off += (bytes + 255) & ~(size_t)255;
        return p;
    };
    int*   deg      = (int*)alloc((size_t)N_NODES * 4);
    float* dinv     = (float*)alloc((size_t)N_NODES * 4);
    int*   offsets  = (int*)alloc((size_t)(N_NODES + 1) * 4);
    int*   cursor   = (int*)alloc((size_t)N_NODES * 4);
    int*   csr_src  = (int*)alloc((size_t)N_EDGES * 4);
    int*   partials = (int*)alloc((size_t)N_SCAN_BLOCKS * 4);
    int*   bases    = (int*)alloc((size_t)N_SCAN_BLOCKS * 4);
    unsigned short* xhi   = (unsigned short*)alloc((size_t)M_PAD * IN_DIM * 2);
    unsigned short* xlo   = (unsigned short*)alloc((size_t)M_PAD * IN_DIM * 2);
    unsigned short* w1thi = (unsigned short*)alloc((size_t)HID_DIM * IN_DIM * 2);
    unsigned short* w1tlo = (unsigned short*)alloc((size_t)HID_DIM * IN_DIM * 2);
    unsigned short* w2thi = (unsigned short*)alloc((size_t)OUT_DIM * HID_DIM * 2);
    unsigned short* w2tlo = (unsigned short*)alloc((size_t)OUT_DIM * HID_DIM * 2);
    float* hs = (float*)alloc((size_t)N_NODES * HID_DIM * 4);

    unsigned short* y1hi = xhi;   // alias dead x regions
    unsigned short* y1lo = xlo;

    // ---- graph prep ----
    hipMemsetAsync(deg, 0, (size_t)N_NODES * 4, stream);
    count_deg_kernel<<<(N_EDGES + 255) / 256, 256, 0, stream>>>(dst, deg, N_EDGES);
    block_sum_kernel<<<N_SCAN_BLOCKS, SCAN_B, 0, stream>>>(deg, partials, N_NODES);
    scan_partials_kernel<<<1, SCAN_B, 0, stream>>>(partials, bases, N_SCAN_BLOCKS);
    finalize_scan_kernel<<<N_SCAN_BLOCKS, SCAN_B, 0, stream>>>(deg, bases, offsets, cursor,
                                                               dinv, N_NODES);
    fill_csr_kernel<<<(N_EDGES + 255) / 256, 256, 0, stream>>>(src, dst, cursor, csr_src, N_EDGES);

    // ---- precision split ----
    long long n4x = (long long)N_NODES * IN_DIM / 4;
    convert_split_kernel<<<(int)((n4x + 255) / 256), 256, 0, stream>>>(x, xhi, xlo, n4x);
    transpose_split_kernel<<<dim3(HID_DIM / 32, IN_DIM / 32), dim3(32, 32), 0, stream>>>(
        W1, w1thi, w1tlo, IN_DIM, HID_DIM);
    transpose_split_kernel<<<dim3(OUT_DIM / 32, HID_DIM / 32), dim3(32, 32), 0, stream>>>(
        W2, w2thi, w2tlo, HID_DIM, OUT_DIM);

    // ---- layer 1 ----
    gemm_bf16x3_kernel<<<dim3(HID_DIM / 128, M_PAD / 128), 256, 0, stream>>>(
        xhi, xlo, w1thi, w1tlo, dinv, hs, N_NODES, HID_DIM, IN_DIM);
    aggregate1_kernel<<<N_NODES, HID_DIM / 4, 0, stream>>>(
        hs, offsets, csr_src, dinv, b1, y1hi, y1lo);

    // ---- layer 2 ----
    gemm_bf16x3_kernel<<<dim3(OUT_DIM / 128, M_PAD / 128), 256, 0, stream>>>(
        y1hi, y1lo, w2thi, w2tlo, dinv, hs, N_NODES, OUT_DIM, HID_DIM);
    aggregate2_kernel<<<N_NODES, OUT_DIM / 4, 0, stream>>>(
        hs, offsets, csr_src, dinv, b2, out);
}